// Round 1
// baseline (437.313 us; speedup 1.0000x reference)
//
#include <hip/hip_runtime.h>

// LIF spike-neuron scan: x [B,S,N] f32, m0 [B,N] f32 ->
//   spikes [B,S,N] (0.0/1.0), m_final [B,N], concatenated flat in d_out (float).
// One thread per (b,n) chain; sequential over t with unroll-16 prefetch.

#define LIF_B 32
#define LIF_S 1024
#define LIF_N 2048
#define LIF_DECAY 0.8f
#define LIF_THRESH 0.5f

__global__ __launch_bounds__(256) void lif_scan_kernel(
    const float* __restrict__ x,
    const float* __restrict__ m0,
    float* __restrict__ spikes,
    float* __restrict__ m_out) {
  const int tid = blockIdx.x * blockDim.x + threadIdx.x;  // tid = b*N + n
  const int b = tid >> 11;          // / LIF_N
  const int n = tid & (LIF_N - 1);  // % LIF_N

  float m = m0[tid];

  // Base offset of (b, t=0, n) in the [B,S,N] tensor.
  size_t base = (size_t)b * LIF_S * LIF_N + (size_t)n;

  constexpr int U = 16;
  #pragma unroll 1
  for (int t = 0; t < LIF_S; t += U) {
    float xv[U];
    // Batch of independent loads -> many outstanding vmem ops.
    #pragma unroll
    for (int j = 0; j < U; ++j) {
      xv[j] = __builtin_nontemporal_load(&x[base + (size_t)(t + j) * LIF_N]);
    }
    #pragma unroll
    for (int j = 0; j < U; ++j) {
      // Match XLA exactly: UNFUSED mul+add (no fma contraction).
      m = __fadd_rn(__fmul_rn(LIF_DECAY, m), xv[j]);
      const bool fired = (m > LIF_THRESH);
      const float sp = fired ? 1.0f : 0.0f;
      __builtin_nontemporal_store(sp, &spikes[base + (size_t)(t + j) * LIF_N]);
      m = fired ? 0.0f : m;  // m * (1 - spike) is exactly 0 or m
    }
  }
  m_out[tid] = m;
}

extern "C" void kernel_launch(void* const* d_in, const int* in_sizes, int n_in,
                              void* d_out, int out_size, void* d_ws, size_t ws_size,
                              hipStream_t stream) {
  const float* x  = (const float*)d_in[0];
  const float* m0 = (const float*)d_in[1];
  float* out = (float*)d_out;
  float* spikes = out;                                        // [B,S,N]
  float* m_out  = out + (size_t)LIF_B * LIF_S * LIF_N;        // [B,N]

  const int total = LIF_B * LIF_N;  // 65536 chains
  const int block = 256;
  const int grid = total / block;   // 256 blocks
  lif_scan_kernel<<<grid, block, 0, stream>>>(x, m0, spikes, m_out);
}